// Round 8
// baseline (290.828 us; speedup 1.0000x reference)
//
#include <hip/hip_runtime.h>

#define DD 256   // in_dim (= 2H)
#define HH 128   // per-branch out dim
#define CC 64    // n_class
#define BB 1024
#define SS1 25
#define SS2 10
#define NN 100000

typedef __attribute__((ext_vector_type(8))) short bf16x8;
typedef __attribute__((ext_vector_type(4))) float f32x4;

__device__ inline unsigned short f2b(float x) {
    union { float f; unsigned u; } v; v.f = x;
    unsigned r = (v.u + 0x7fffu + ((v.u >> 16) & 1u)) >> 16;
    return (unsigned short)r;
}
__device__ inline float b2f(unsigned u16) {
    union { unsigned u; float f; } v; v.u = u16 << 16;
    return v.f;
}

// ---------------------------------------------------------------------------
// W prep: [Wx1 | Wn1] fp32 [256][128]x2 -> bf16, MFMA B-fragment order:
//   frag = kc*16 + nt  (kc<8, nt<16; nt<8 -> Wx cols, nt>=8 -> Wn cols)
//   Wsw[(frag*64 + lane)*8 + j] = Wcat[kc*32 + (lane>>4)*8 + j][nt*16 + (lane&15)]
// ---------------------------------------------------------------------------
__global__ __launch_bounds__(256)
void prep_w(const float* __restrict__ Wx, const float* __restrict__ Wn,
            unsigned short* __restrict__ Wsw) {
    const int t    = blockIdx.x * 256 + threadIdx.x;   // 0..8191
    const int lane = t & 63;
    const int frag = t >> 6;                           // kc*16 + nt
    const int kc = frag >> 4, nt = frag & 15;
    const int quad = lane >> 4, lr = lane & 15;
    unsigned short v[8];
#pragma unroll
    for (int j = 0; j < 8; ++j) {
        int k = kc * 32 + quad * 8 + j;
        int n = nt * 16 + lr;                          // 0..255
        float w = (n < HH) ? Wx[k * HH + n] : Wn[k * HH + (n - HH)];
        v[j] = f2b(w);
    }
    ((uint4*)Wsw)[t] = *(uint4*)v;
}

// ---------------------------------------------------------------------------
// PQ = feat @ [Wx1 | Wn1] -> bf16 [NN][256]
// v5: BARRIER-FREE, wave-private GEMM. Each wave owns 32 rows x 128 cols:
//   wave w: rows r0 = blk*64 + (w&1)*32, cols ch=(w>>1)*128.
// A is loaded DIRECTLY from global in fragment order (lane reads
// feat[row=lr / 16+lr][kc*32+quad*8 .. +8] as two float4 -> per-instruction
// the wave covers 16 rows x full 128-B windows, so cacheline efficiency is
// unchanged) and converted to bf16 in registers. No LDS staging, no
// __syncthreads anywhere -> loads/MFMAs of 16 waves/CU co-schedule freely
// (rounds 6/7 were barrier-serialized at 1.65 TB/s; compiler kept sinking
// staging loads, VGPR 56). Epilogue transposes C through a wave-PRIVATE
// LDS region (in-wave dep only), then fully-coalesced 256-B row stores.
// LDS 4 x 8448 B = 33.8 KB -> 4 blocks/CU.
// ---------------------------------------------------------------------------
__global__ __launch_bounds__(256, 4)
void pq_gemm(const float* __restrict__ feat,
             const unsigned short* __restrict__ Wsw,
             unsigned short* __restrict__ PQb) {
    constexpr int LS = 132;                  // bf16 row stride (264 B)
    __shared__ unsigned short sO[4][32 * LS];   // 8448 B per wave
    const int t    = threadIdx.x;
    const int w    = t >> 6, lane = t & 63;
    const int quad = lane >> 4, lr = lane & 15;
    const int rp   = w & 1, ch = w >> 1;
    const long r0  = (long)blockIdx.x * 64 + rp * 32;

    long rowA = r0 + lr;       if (rowA > NN - 1) rowA = NN - 1;
    long rowB = r0 + 16 + lr;  if (rowB > NN - 1) rowB = NN - 1;
    const float* pA = feat + rowA * DD + quad * 8;
    const float* pB = feat + rowB * DD + quad * 8;

    f32x4 acc[2][8] = {};
#pragma unroll
    for (int kc = 0; kc < 8; ++kc) {
        float4 x0 = *(const float4*)(pA + kc * 32);
        float4 x1 = *(const float4*)(pA + kc * 32 + 4);
        float4 y0 = *(const float4*)(pB + kc * 32);
        float4 y1 = *(const float4*)(pB + kc * 32 + 4);
        unsigned short ua[8] = { f2b(x0.x), f2b(x0.y), f2b(x0.z), f2b(x0.w),
                                 f2b(x1.x), f2b(x1.y), f2b(x1.z), f2b(x1.w) };
        unsigned short ub[8] = { f2b(y0.x), f2b(y0.y), f2b(y0.z), f2b(y0.w),
                                 f2b(y1.x), f2b(y1.y), f2b(y1.z), f2b(y1.w) };
        bf16x8 a0 = *(bf16x8*)ua;
        bf16x8 a1 = *(bf16x8*)ub;
#pragma unroll
        for (int ntl = 0; ntl < 8; ++ntl) {
            bf16x8 b = *(const bf16x8*)&Wsw[((kc * 16 + ch * 8 + ntl) * 64 + lane) * 8];
            acc[0][ntl] = __builtin_amdgcn_mfma_f32_16x16x32_bf16(a0, b, acc[0][ntl], 0, 0, 0);
            acc[1][ntl] = __builtin_amdgcn_mfma_f32_16x16x32_bf16(a1, b, acc[1][ntl], 0, 0, 0);
        }
    }

    // epilogue (wave-private): C/D layout row=quad*4+r, col=lr
    unsigned short* O = sO[w];
#pragma unroll
    for (int rg = 0; rg < 2; ++rg)
#pragma unroll
        for (int ntl = 0; ntl < 8; ++ntl) {
#pragma unroll
            for (int r = 0; r < 4; ++r)
                O[(rg * 16 + quad * 4 + r) * LS + ntl * 16 + lr]
                    = f2b(acc[rg][ntl][r]);
        }

    // readback + coalesced stores: 32 rows x 16 chunks of 16 B (256 B/row)
#pragma unroll
    for (int i = 0; i < 8; ++i) {
        int id = i * 64 + lane;
        int row = id >> 4, c = id & 15;
        long gr = r0 + row;
        if (gr < NN) {
            uint4 d = *(uint4*)&O[row * LS + c * 8];
            *(uint4*)&PQb[gr * DD + ch * 128 + c * 8] = d;
        }
    }
}

// ---------------------------------------------------------------------------
// build_g1: g1b[row] = bf16(relu([PQ[ids1[row]].X + bx1 | mean_j PQ[ids2].N + bn1]))
// 2 rows per wave (half-wave each, 8 B/lane); 10 neighbor ids via shfl.
// ---------------------------------------------------------------------------
__global__ __launch_bounds__(256)
void build_g1(const unsigned short* __restrict__ PQb,
              const int* __restrict__ ids1, const int* __restrict__ ids2,
              const float* __restrict__ bx1, const float* __restrict__ bn1,
              unsigned short* __restrict__ g1b) {
    const int wv   = threadIdx.x >> 6;
    const int lane = threadIdx.x & 63;
    const int sub  = lane >> 5, lr = lane & 31;
    const int row  = blockIdx.x * 8 + wv * 2 + sub;

    long xr = (long)ids1[row];
    uint2 xv = *(const uint2*)&PQb[xr * DD + lr * 4];

    int myid = ids2[row * SS2 + (lr % SS2)];
    float4 acc = {0.f, 0.f, 0.f, 0.f};
#pragma unroll
    for (int j = 0; j < SS2; ++j) {
        long nr = (long)__shfl(myid, (lane & 32) + j);
        uint2 nv = *(const uint2*)&PQb[nr * DD + HH + lr * 4];
        acc.x += b2f(nv.x & 0xffff); acc.y += b2f(nv.x >> 16);
        acc.z += b2f(nv.y & 0xffff); acc.w += b2f(nv.y >> 16);
    }
    float4 bx = *(const float4*)&bx1[lr * 4];
    float4 bn = *(const float4*)&bn1[lr * 4];
    float x0 = fmaxf(b2f(xv.x & 0xffff) + bx.x, 0.f);
    float x1 = fmaxf(b2f(xv.x >> 16)    + bx.y, 0.f);
    float x2 = fmaxf(b2f(xv.y & 0xffff) + bx.z, 0.f);
    float x3 = fmaxf(b2f(xv.y >> 16)    + bx.w, 0.f);
    constexpr float inv = 1.f / SS2;
    float n0 = fmaxf(acc.x * inv + bn.x, 0.f);
    float n1 = fmaxf(acc.y * inv + bn.y, 0.f);
    float n2 = fmaxf(acc.z * inv + bn.z, 0.f);
    float n3 = fmaxf(acc.w * inv + bn.w, 0.f);

    uint2 ox = { (unsigned)f2b(x0) | ((unsigned)f2b(x1) << 16),
                 (unsigned)f2b(x2) | ((unsigned)f2b(x3) << 16) };
    uint2 on = { (unsigned)f2b(n0) | ((unsigned)f2b(n1) << 16),
                 (unsigned)f2b(n2) | ((unsigned)f2b(n3) << 16) };
    *(uint2*)&g1b[(long)row * DD + lr * 4]      = ox;
    *(uint2*)&g1b[(long)row * DD + HH + lr * 4] = on;
}

// ---------------------------------------------------------------------------
// build_g0: g0[row] = relu([PQ[ids0[row]].X + bx1 | mean_{j<25} PQ[ids1].N + bn1])
// fp32 output; 2 rows per wave.
// ---------------------------------------------------------------------------
__global__ __launch_bounds__(256)
void build_g0(const unsigned short* __restrict__ PQb,
              const int* __restrict__ ids0, const int* __restrict__ ids1,
              const float* __restrict__ bx1, const float* __restrict__ bn1,
              float* __restrict__ g0) {
    const int wv   = threadIdx.x >> 6;
    const int lane = threadIdx.x & 63;
    const int sub  = lane >> 5, lr = lane & 31;
    const int row  = blockIdx.x * 8 + wv * 2 + sub;

    long xr = (long)ids0[row];
    uint2 xv = *(const uint2*)&PQb[xr * DD + lr * 4];

    int myid = ids1[row * SS1 + (lr % SS1)];
    float4 acc = {0.f, 0.f, 0.f, 0.f};
#pragma unroll 5
    for (int j = 0; j < SS1; ++j) {
        long nr = (long)__shfl(myid, (lane & 32) + j);
        uint2 nv = *(const uint2*)&PQb[nr * DD + HH + lr * 4];
        acc.x += b2f(nv.x & 0xffff); acc.y += b2f(nv.x >> 16);
        acc.z += b2f(nv.y & 0xffff); acc.w += b2f(nv.y >> 16);
    }
    float4 bx = *(const float4*)&bx1[lr * 4];
    float4 bn = *(const float4*)&bn1[lr * 4];
    constexpr float inv = 1.f / SS1;
    float4 xo = { fmaxf(b2f(xv.x & 0xffff) + bx.x, 0.f),
                  fmaxf(b2f(xv.x >> 16)    + bx.y, 0.f),
                  fmaxf(b2f(xv.y & 0xffff) + bx.z, 0.f),
                  fmaxf(b2f(xv.y >> 16)    + bx.w, 0.f) };
    float4 no = { fmaxf(acc.x * inv + bn.x, 0.f),
                  fmaxf(acc.y * inv + bn.y, 0.f),
                  fmaxf(acc.z * inv + bn.z, 0.f),
                  fmaxf(acc.w * inv + bn.w, 0.f) };
    *(float4*)&g0[(long)row * DD + lr * 4]      = xo;
    *(float4*)&g0[(long)row * DD + HH + lr * 4] = no;
}

// ---------------------------------------------------------------------------
// gm_mean: gm[i][:] = mean over SS1 of g1b rows (bf16 -> fp32), 4 rows/block
// ---------------------------------------------------------------------------
__global__ __launch_bounds__(256)
void gm_mean(const unsigned short* __restrict__ g1b, float* __restrict__ gm) {
    const int row  = blockIdx.x * 4 + (threadIdx.x >> 6);
    const int lane = threadIdx.x & 63;
    const unsigned short* base = g1b + (long)row * SS1 * DD + lane * 4;
    float4 acc = {0.f, 0.f, 0.f, 0.f};
#pragma unroll 5
    for (int j = 0; j < SS1; ++j) {
        uint2 u = *(const uint2*)(base + (long)j * DD);
        acc.x += b2f(u.x & 0xffff); acc.y += b2f(u.x >> 16);
        acc.z += b2f(u.y & 0xffff); acc.w += b2f(u.y >> 16);
    }
    constexpr float inv = 1.f / SS1;
    float4 o = { acc.x * inv, acc.y * inv, acc.z * inv, acc.w * inv };
    *(float4*)&gm[(long)row * DD + lane * 4] = o;
}

// ---------------------------------------------------------------------------
// agg2 (column-split, 64x2 grid = 128 blocks):
//   by=0: f0[i][0:128]   = g0[i] . Wx2 + bx2
//   by=1: f0[i][128:256] = gm[i] . Wn2 + bn2
// ---------------------------------------------------------------------------
__global__ __launch_bounds__(256)
void agg2(const float* __restrict__ g0, const float* __restrict__ gm,
          const float* __restrict__ Wx, const float* __restrict__ bx,
          const float* __restrict__ Wn, const float* __restrict__ bn,
          float* __restrict__ f0) {
    constexpr int RT = 16;
    __shared__ float A[RT][DD];
    const int r0 = blockIdx.x * RT;
    const int by = blockIdx.y;                 // 0=X half, 1=N half
    const int t  = threadIdx.x;
    const float* __restrict__ src = by ? gm : g0;
    const float* __restrict__ W   = by ? Wn : Wx;
    const float* __restrict__ bb  = by ? bn : bx;

#pragma unroll
    for (int i = 0; i < 4; ++i) {
        int id = i * 256 + t;
        int r = id >> 6, c4 = (id & 63) * 4;
        *(float4*)&A[r][c4] = *(const float4*)(src + (long)(r0 + r) * DD + c4);
    }
    __syncthreads();

    const int c  = t & 127;
    const int rh = t >> 7;                     // 0/1: rows rh*8..rh*8+7
    float acc[8];
#pragma unroll
    for (int r = 0; r < 8; ++r) acc[r] = 0.f;
#pragma unroll 4
    for (int k = 0; k < DD; ++k) {
        float wv = W[k * HH + c];
#pragma unroll
        for (int r = 0; r < 8; ++r) acc[r] += A[rh * 8 + r][k] * wv;
    }
    const float bias = bb[c];
#pragma unroll
    for (int r = 0; r < 8; ++r)
        f0[(long)(r0 + rh * 8 + r) * DD + by * HH + c] = acc[r] + bias;
}

// ---------------------------------------------------------------------------
// head: out[1024][64] = f0 @ Wfc + bfc; 64 blocks x 16 rows.
// ---------------------------------------------------------------------------
__global__ __launch_bounds__(256)
void head_kernel(const float* __restrict__ f0, const float* __restrict__ Wfc,
                 const float* __restrict__ bfc, float* __restrict__ out) {
    constexpr int RT = 16;
    __shared__ float aX[RT][DD];
    const int r0 = blockIdx.x * RT;
    const int t  = threadIdx.x;

#pragma unroll
    for (int i = 0; i < 4; ++i) {
        int id = i * 256 + t;
        int r = id >> 6, c4 = (id & 63) * 4;
        *(float4*)&aX[r][c4] = *(const float4*)(f0 + (long)(r0 + r) * DD + c4);
    }
    __syncthreads();

    const int c  = t & (CC - 1);
    const int rg = t >> 6;                    // 0..3 -> rows rg*4..rg*4+3
    float acc[4];
#pragma unroll
    for (int r = 0; r < 4; ++r) acc[r] = 0.f;
#pragma unroll 4
    for (int k = 0; k < DD; ++k) {
        float wv = Wfc[k * CC + c];
#pragma unroll
        for (int r = 0; r < 4; ++r) acc[r] += aX[rg * 4 + r][k] * wv;
    }
    const float bias = bfc[c];
#pragma unroll
    for (int r = 0; r < 4; ++r)
        out[(long)(r0 + rg * 4 + r) * CC + c] = acc[r] + bias;
}

// ---------------------------------------------------------------------------
extern "C" void kernel_launch(void* const* d_in, const int* in_sizes, int n_in,
                              void* d_out, int out_size, void* d_ws, size_t ws_size,
                              hipStream_t stream) {
    const int*   ids0 = (const int*)d_in[0];
    const int*   ids1 = (const int*)d_in[1];
    const int*   ids2 = (const int*)d_in[2];
    const float* feat = (const float*)d_in[3];
    const float* Wx1  = (const float*)d_in[4];
    const float* bx1  = (const float*)d_in[5];
    const float* Wn1  = (const float*)d_in[6];
    const float* bn1  = (const float*)d_in[7];
    const float* Wx2  = (const float*)d_in[8];
    const float* bx2  = (const float*)d_in[9];
    const float* Wn2  = (const float*)d_in[10];
    const float* bn2  = (const float*)d_in[11];
    const float* Wfc  = (const float*)d_in[12];
    const float* bfc  = (const float*)d_in[13];
    float* out = (float*)d_out;

    const long M1 = (long)BB * SS1;                      // 25600
    float* wsf = (float*)d_ws;
    float* g0 = wsf;  wsf += (long)BB * DD;              // 1 MB
    float* gm = wsf;  wsf += (long)BB * DD;              // 1 MB
    float* f0 = wsf;  wsf += (long)BB * DD;              // 1 MB
    unsigned short* PQb = (unsigned short*)wsf;          // 51.2 MB
    unsigned short* g1b = PQb + (long)NN * DD;           // 13.1 MB
    unsigned short* Wsw = g1b + M1 * DD;                 // 128 KB

    // 1) W prep (bf16 + B-fragment swizzle of [Wx1|Wn1])
    prep_w<<<32, 256, 0, stream>>>(Wx1, Wn1, Wsw);
    // 2) PQ = feat @ [Wx1|Wn1]  (bf16)                  [100000,256]
    pq_gemm<<<(NN + 63) / 64, 256, 0, stream>>>(feat, Wsw, PQb);
    // 3) g1 (bf16)                                      [25600,256]
    build_g1<<<M1 / 8, 256, 0, stream>>>(PQb, ids1, ids2, bx1, bn1, g1b);
    // 4) g0 (fp32)                                      [1024,256]
    build_g0<<<BB / 8, 256, 0, stream>>>(PQb, ids0, ids1, bx1, bn1, g0);
    // 5) gm = mean over S1 of g1 rows                   [1024,256]
    gm_mean<<<BB / 4, 256, 0, stream>>>(g1b, gm);
    // 6) f0 = [g0.Wx2 | gm.Wn2]  (column-split grid)    [1024,256]
    agg2<<<dim3(BB / 16, 2), 256, 0, stream>>>(g0, gm, Wx2, bx2, Wn2, bn2, f0);
    // 7) out = f0 @ Wfc + bfc                           [1024,64]
    head_kernel<<<BB / 16, 256, 0, stream>>>(f0, Wfc, bfc, out);
}